// Round 7
// baseline (315.266 us; speedup 1.0000x reference)
//
#include <hip/hip_runtime.h>
#include <hip/hip_bf16.h>
#include <math.h>

typedef short bf16x8 __attribute__((ext_vector_type(8)));
typedef float f32x4  __attribute__((ext_vector_type(4)));

struct G157 { float g3[3], g5[5], g7[7]; };

__device__ __forceinline__ unsigned short f2bf(float f) {
  __hip_bfloat16 h = __float2bfloat16(f);     // RNE
  return *reinterpret_cast<unsigned short*>(&h);
}

// zero out + S; block 0 builds the MFMA weight fragment table Wf[3][64][8] bf16.
// Wf[cls][lane=i+16*kq][j] = banded composed-conv weight W(i, k=kq*8+j) =
//   wtab_row(pos(i,cls))[k-i-2] (0 outside band). Same table serves A (v-pass)
//   and B (h-pass) fragments by symmetry of the construction.
__global__ __launch_bounds__(256) void zero_k(float* __restrict__ out, float* __restrict__ S,
                                              unsigned short* __restrict__ Wf, G157 gw) {
  __shared__ float wt[256 * 13];
  int i = blockIdx.x * 256 + threadIdx.x;
  if (i < 65536) out[i] = 0.f;
  if (i < 1024) S[i] = 0.f;
  if (blockIdx.x != 0) return;
  {
    int g = threadIdx.x;  // position 0..255
    float row[13];
    #pragma unroll
    for (int t = 0; t < 13; ++t) row[t] = 0.f;
    #pragma unroll
    for (int di = -3; di <= 3; ++di) {
      int ii = g + di;
      if ((unsigned)ii >= 256u) continue;
      float w7 = gw.g7[di + 3];
      #pragma unroll
      for (int dj = -2; dj <= 2; ++dj) {
        int jj = ii + dj;
        if ((unsigned)jj >= 256u) continue;
        float c2 = w7 * gw.g5[dj + 2];
        #pragma unroll
        for (int dk = -1; dk <= 1; ++dk) {
          int mm = jj + dk;
          if ((unsigned)mm >= 256u) continue;
          row[di + dj + dk + 6] += c2 * gw.g3[dk + 1];
        }
      }
    }
    #pragma unroll
    for (int t = 0; t < 13; ++t) wt[g * 13 + t] = row[t];
  }
  __syncthreads();
  int t = threadIdx.x;
  if (t < 192) {
    int cls = t >> 6, lane = t & 63;
    int mm = lane & 15, kq = lane >> 4;
    int grow = (cls == 0) ? mm : ((cls == 1) ? 128 + mm : 240 + mm);
    unsigned short v[8];
    #pragma unroll
    for (int j = 0; j < 8; ++j) {
      int k = kq * 8 + j, tt = k - mm - 2;
      v[j] = (tt >= 0 && tt < 13) ? f2bf(wt[grow * 13 + tt]) : (unsigned short)0;
    }
    uint4 q;
    q.x = v[0] | ((unsigned)v[1] << 16); q.y = v[2] | ((unsigned)v[3] << 16);
    q.z = v[4] | ((unsigned)v[5] << 16); q.w = v[6] | ((unsigned)v[7] << 16);
    *(uint4*)(Wf + (size_t)t * 8) = q;
  }
}

// MFMA blur: block = 64x64 pixel tile of one image.
// v-pass: V = Wv(banded) @ Xwin per 16x16 tile (20 tiles incl. +-8 col halo)
// h-pass: H = Vwin @ Wh(banded); ctx = x - H (fp32 x from LDS), bf16 out,
// stored TRANSPOSED per image (n' = col*256 + row) - Gram matrix is invariant
// to consistent pixel permutation. exp-sum accumulated to S.
__global__ __launch_bounds__(256) void ctx_m(const float* __restrict__ x,
                                             unsigned short* __restrict__ ctxT,
                                             float* __restrict__ S,
                                             const unsigned short* __restrict__ Wf) {
  __shared__ __align__(16) float xf[80 * 86];            // fp32 halo, stride 86
  __shared__ __align__(16) unsigned short Vl[64 * 128];  // bf16 V, 256B rows, XOR-swizzled
  __shared__ __align__(16) unsigned char sc[4][2048];    // per-wave store bounce

  const int tid = threadIdx.x;
  const int img = blockIdx.x >> 4;
  const int tile = blockIdx.x & 15;
  const int ty = tile >> 2, tx = tile & 3;
  const int OY = ty << 6, OX = tx << 6;
  const float* xg = x + ((size_t)img << 16);

  const int wv = tid >> 6, lane = tid & 63;
  const int m = lane & 15, kq = lane >> 4;

  bf16x8 wf0 = *(const bf16x8*)(Wf + (size_t)lane * 8);
  bf16x8 wf1 = *(const bf16x8*)(Wf + (size_t)(64 + lane) * 8);
  bf16x8 wf2 = *(const bf16x8*)(Wf + (size_t)(128 + lane) * 8);

  // ---- stage x fp32 halo: rows OY-8..OY+71, cols OX-8..OX+71
  for (int u = tid; u < 1600; u += 256) {
    int r = u / 20, c = u % 20;
    int gy = OY - 8 + r, gx = OX - 8 + (c << 2);
    float4 v = make_float4(0.f, 0.f, 0.f, 0.f);
    if ((unsigned)gy < 256u) {
      const float* rp = xg + gy * 256 + gx;
      if (gx >= 0 && gx + 3 < 256) v = *(const float4*)rp;
      else {
        if ((unsigned)(gx + 0) < 256u) v.x = rp[0];
        if ((unsigned)(gx + 1) < 256u) v.y = rp[1];
        if ((unsigned)(gx + 2) < 256u) v.z = rp[2];
        if ((unsigned)(gx + 3) < 256u) v.w = rp[3];
      }
    }
    float* d = &xf[r * 86 + (c << 2)];
    *(float2*)d = make_float2(v.x, v.y);          // stride 86 (odd*2): b64-aligned
    *(float2*)(d + 2) = make_float2(v.z, v.w);
  }
  __syncthreads();

  // ---- v-pass: wave wv -> tiles (ry=0..3, cv=wv) + (ry=wv, cv=4)
  #pragma unroll
  for (int tl = 0; tl < 5; ++tl) {
    const int ry = (tl < 4) ? tl : wv;
    const int cv = (tl < 4) ? wv : 4;
    const int gi = (ty << 2) + ry;
    bf16x8 wa = (gi == 0) ? wf0 : ((gi == 15) ? wf2 : wf1);
    bf16x8 xb;
    #pragma unroll
    for (int j = 0; j < 8; ++j) {   // B[k][n]: k = kq*8+j down x-rows, n = m
      float xv = xf[(ry * 16 + kq * 8 + j) * 86 + cv * 16 + m];
      xb[j] = (short)f2bf(xv);
    }
    f32x4 acc = {0.f, 0.f, 0.f, 0.f};
    acc = __builtin_amdgcn_mfma_f32_16x16x32_bf16(wa, xb, acc, 0, 0, 0);
    #pragma unroll
    for (int reg = 0; reg < 4; ++reg) {           // C: row=kq*4+reg, col=m
      int row = ry * 16 + kq * 4 + reg;
      int cb = (cv * 16 + m) << 1;                // col byte 0..158
      int off = (row << 8) + (cb ^ ((row & 7) << 4));
      *(unsigned short*)((char*)Vl + off) = f2bf(acc[reg]);
    }
  }
  __syncthreads();

  // ---- h-pass: wave wv -> col-tile cx=wv, 4 tiles ry=0..3
  const int gj = (tx << 2) + wv;
  bf16x8 wb = (gj == 0) ? wf0 : ((gj == 15) ? wf2 : wf1);
  float esum = 0.f;
  #pragma unroll
  for (int ry = 0; ry < 4; ++ry) {
    int row = ry * 16 + m;                         // A row = m (lane&15)
    int off = (row << 8) + ((((wv << 5) + (kq << 4)) ^ ((m & 7) << 4)));
    bf16x8 va = *(const bf16x8*)((const char*)Vl + off);
    f32x4 acc = {0.f, 0.f, 0.f, 0.f};
    acc = __builtin_amdgcn_mfma_f32_16x16x32_bf16(va, wb, acc, 0, 0, 0);
    unsigned short hs[4];
    #pragma unroll
    for (int reg = 0; reg < 4; ++reg) {            // D: row=kq*4+reg (y), col=m (c)
      int yl = ry * 16 + kq * 4 + reg;
      float xv = xf[(8 + yl) * 86 + 8 + wv * 16 + m];
      float cvv = xv - acc[reg];
      esum += __expf(cvv);
      hs[reg] = f2bf(cvv);
    }
    int sb = (m << 7) + (((ry << 5) + (kq << 3)) ^ ((m & 7) << 4));
    *(uint2*)(&sc[wv][sb]) =
        make_uint2(hs[0] | ((unsigned)hs[1] << 16), hs[2] | ((unsigned)hs[3] << 16));
  }
  // coalesced transposed store: 16 cols x 64 y per wave (same-wave DS: in-order)
  {
    int c = lane >> 2, s = lane & 3;
    #pragma unroll
    for (int u = 0; u < 2; ++u) {
      int sb = (c << 7) + ((((s << 5) + (u << 4)) ^ ((c & 7) << 4)));
      uint4 q = *(uint4*)(&sc[wv][sb]);
      int gcol = OX + wv * 16 + c;
      int gy0 = OY + s * 16 + u * 8;
      *(uint4*)(ctxT + ((size_t)img << 16) + (gcol << 8) + gy0) = q;
    }
  }
  #pragma unroll
  for (int o = 32; o >= 1; o >>= 1) esum += __shfl_down(esum, o);
  if (lane == 0) atomicAdd(&S[img], esum);
}

// MFMA att: per batch b, att = P * C^T, P = exp(C); divide by S before atomicAdd.
__global__ __launch_bounds__(256) void att_k(const unsigned short* __restrict__ ctxb,
                                             const float* __restrict__ S,
                                             float* __restrict__ attacc) {
  const int t = threadIdx.x;
  const int wv = t >> 6, lane = t & 63;
  const int rw = lane & 15;
  const int kq = lane >> 4;
  const int ci = blockIdx.x;       // 64 chunks of 1024
  const int b = blockIdx.y;        // 16 batches
  const unsigned short* cb = ctxb + ((size_t)b << 22);
  const int n0 = (ci << 10) + (kq << 3);

  const unsigned short* pA = cb + (((size_t)(16 * wv + rw)) << 16) + n0;
  const unsigned short* pB = cb + (((size_t)rw) << 16) + n0;

  f32x4 acc0 = {0.f, 0.f, 0.f, 0.f}, acc1 = acc0, acc2 = acc0, acc3 = acc0;

  #pragma unroll 8
  for (int ks = 0; ks < 1024; ks += 32) {
    bf16x8 av = *(const bf16x8*)(pA + ks);
    bf16x8 ev;
    const unsigned* au = (const unsigned*)&av;
    unsigned* eu = (unsigned*)&ev;
    #pragma unroll
    for (int j = 0; j < 4; ++j) {
      unsigned w = au[j];
      float lo = __uint_as_float(w << 16);
      float hi = __uint_as_float(w & 0xffff0000u);
      eu[j] = ((unsigned)f2bf(__expf(hi)) << 16) | (unsigned)f2bf(__expf(lo));
    }
    bf16x8 b0 = *(const bf16x8*)(pB + ks);
    bf16x8 b1 = *(const bf16x8*)(pB + (size_t)(16 << 16) + ks);
    bf16x8 b2 = *(const bf16x8*)(pB + (size_t)(32 << 16) + ks);
    bf16x8 b3 = *(const bf16x8*)(pB + (size_t)(48 << 16) + ks);
    acc0 = __builtin_amdgcn_mfma_f32_16x16x32_bf16(ev, b0, acc0, 0, 0, 0);
    acc1 = __builtin_amdgcn_mfma_f32_16x16x32_bf16(ev, b1, acc1, 0, 0, 0);
    acc2 = __builtin_amdgcn_mfma_f32_16x16x32_bf16(ev, b2, acc2, 0, 0, 0);
    acc3 = __builtin_amdgcn_mfma_f32_16x16x32_bf16(ev, b3, acc3, 0, 0, 0);
  }

  const int dl = kq << 2;
  float* ap = attacc + (((size_t)((b << 6) + (wv << 4) + dl)) << 6) + rw;
  #pragma unroll
  for (int reg = 0; reg < 4; ++reg) {
    float inv = 1.0f / S[(b << 6) + (wv << 4) + dl + reg];
    atomicAdd(ap + ((size_t)reg << 6) + 0,  acc0[reg] * inv);
    atomicAdd(ap + ((size_t)reg << 6) + 16, acc1[reg] * inv);
    atomicAdd(ap + ((size_t)reg << 6) + 32, acc2[reg] * inv);
    atomicAdd(ap + ((size_t)reg << 6) + 48, acc3[reg] * inv);
  }
}

extern "C" void kernel_launch(void* const* d_in, const int* in_sizes, int n_in,
                              void* d_out, int out_size, void* d_ws, size_t ws_size,
                              hipStream_t stream) {
  const float* x = (const float*)d_in[0];
  float* out = (float*)d_out;
  unsigned short* ctxb = (unsigned short*)d_ws;                           // 134 MiB bf16
  float* S = (float*)((char*)d_ws + (size_t)67108864 * 2);                // 4 KB
  unsigned short* Wf = (unsigned short*)((char*)d_ws + (size_t)67108864 * 2 + 4096); // 3 KB
  if (ws_size < (size_t)67108864 * 2 + 4096 + 4096) return;

  // per-level 1-D gaussians in double (matches cv2.getGaussianKernel)
  double gg[3][7];
  double sv = pow(2.0, 1.0 / 3.0);
  for (int lv = 0; lv < 3; ++lv) {
    int k = 2 * lv + 3;
    double sig = 1.6 * pow(sv, lv), sum = 0.0;
    for (int i = 0; i < k; ++i) {
      double a = i - (k - 1) / 2.0;
      gg[lv][i] = exp(-a * a / (2.0 * sig * sig));
      sum += gg[lv][i];
    }
    for (int i = 0; i < k; ++i) gg[lv][i] /= sum;
  }

  G157 gw;
  for (int i = 0; i < 3; ++i) gw.g3[i] = (float)gg[0][i];
  for (int i = 0; i < 5; ++i) gw.g5[i] = (float)gg[1][i];
  for (int i = 0; i < 7; ++i) gw.g7[i] = (float)gg[2][i];

  zero_k<<<dim3(256), dim3(256), 0, stream>>>(out, S, Wf, gw);
  ctx_m<<<dim3(16384), dim3(256), 0, stream>>>(x, ctxb, S, Wf);
  att_k<<<dim3(64, 16), dim3(256), 0, stream>>>(ctxb, S, out);
}

// Round 8
// 186.016 us; speedup vs baseline: 1.6948x; 1.6948x over previous
//
#include <hip/hip_runtime.h>
#include <hip/hip_bf16.h>
#include <math.h>

typedef short bf16x8 __attribute__((ext_vector_type(8)));
typedef float f32x4  __attribute__((ext_vector_type(4)));

struct WC   { float c[13]; };                 // interior composed 13-tap
struct G157 { float g3[3], g5[5], g7[7]; };   // per-level 1-D gaussians

__device__ __forceinline__ unsigned short f2bf(float f) {
  __hip_bfloat16 h = __float2bfloat16(f);     // RNE
  return *reinterpret_cast<unsigned short*>(&h);
}
__device__ __forceinline__ float bf2f(unsigned short s) {
  return __uint_as_float((unsigned)s << 16);
}

// zero out + S; block 0 builds per-position composed weight table wtab[256][16]
__global__ __launch_bounds__(256) void zero_k(float* __restrict__ out, float* __restrict__ S,
                                              float* __restrict__ wtab, G157 gw) {
  int i = blockIdx.x * 256 + threadIdx.x;
  if (i < 65536) out[i] = 0.f;
  if (i < 1024) S[i] = 0.f;
  if (blockIdx.x == 0) {
    int g = threadIdx.x;
    float row[13];
    #pragma unroll
    for (int t = 0; t < 13; ++t) row[t] = 0.f;
    #pragma unroll
    for (int di = -3; di <= 3; ++di) {
      int ii = g + di;
      if ((unsigned)ii >= 256u) continue;
      float w7 = gw.g7[di + 3];
      #pragma unroll
      for (int dj = -2; dj <= 2; ++dj) {
        int jj = ii + dj;
        if ((unsigned)jj >= 256u) continue;
        float c2 = w7 * gw.g5[dj + 2];
        #pragma unroll
        for (int dk = -1; dk <= 1; ++dk) {
          int mm = jj + dk;
          if ((unsigned)mm >= 256u) continue;
          row[di + dj + dk + 6] += c2 * gw.g3[dk + 1];
        }
      }
    }
    #pragma unroll
    for (int t = 0; t < 13; ++t) wtab[(g << 4) + t] = row[t];
    wtab[(g << 4) + 13] = 0.f; wtab[(g << 4) + 14] = 0.f; wtab[(g << 4) + 15] = 0.f;
  }
}

// ctx = x - blur(x), bf16 out. v-conv per-column register window (fully unrolled ring),
// h-conv in 4-cols/lane layout with aligned ds_read_b128. Edge cols (0..5,250..255)
// fixed exactly in an in-block post-pass from saved v-results. NO exp here (att_k owns S).
__global__ __launch_bounds__(256) void ctx_k(const float* __restrict__ x,
                                             unsigned short* __restrict__ ctxb,
                                             const float* __restrict__ wtab,
                                             WC wc) {
  __shared__ __align__(16) float rb[2][4][272];   // v-results: 8 pad | 256 | 8 pad
  __shared__ __align__(16) float xrb[2][4][256];  // x rows (for ctx = x - h)
  __shared__ float vs[64][24];                    // v-results at cols 0..11 / 244..255
  __shared__ float wl[96];                        // boundary rows 0..5 (x16)

  const int tid = threadIdx.x;
  const int img = blockIdx.x >> 2;
  const int band = blockIdx.x & 3;
  const int y0 = band << 6;
  const float* xg = x + ((size_t)img << 16);
  unsigned short* cgb = ctxb + ((size_t)img << 16);

  if (tid < 96) wl[tid] = wtab[tid];
  if (tid < 128) {  // zero rb pads once
    int bb = (tid >> 6) & 1, rr = (tid >> 4) & 3, pp = tid & 15;
    rb[bb][rr][(pp < 8) ? pp : (256 + pp)] = 0.f;
  }

  // input ring: slot(row) = (row - y0 + 6) mod 24. Init rows y0-6 .. y0+13.
  float win[24];
  #pragma unroll
  for (int i = 0; i < 24; ++i) win[i] = 0.f;
  #pragma unroll
  for (int i = 0; i < 20; ++i) {
    int yy = y0 - 6 + i;
    if ((unsigned)yy < 256u) win[i] = xg[yy * 256 + tid];
  }
  __syncthreads();

  const bool vsave = (tid < 12) || (tid >= 244);
  const int vsidx = (tid < 12) ? tid : (tid - 232);
  const int g = tid >> 6, q = tid & 63;   // h-phase: wave g -> row, lane q -> cols 4q..4q+3

  #pragma unroll
  for (int it = 0; it < 16; ++it) {
    const int y = y0 + 4 * it;
    // prefetch rows y+14..y+17 (2-iteration lookahead); band needs rows up to y0+69
    #pragma unroll
    for (int j = 0; j < 4; ++j) {
      if (4 * it + 14 + j < 70) {
        int yy = y + 14 + j;
        float v = 0.f;
        if (yy < 256) v = xg[yy * 256 + tid];
        win[(4 * it + 20 + j) % 24] = v;
      }
    }
    // vertical conv, 4 rows, per-column (compile-time ring indices)
    float vv[4];
    if (it > 1 && it < 14) {  // rows y0+8..y0+55: always interior
      #pragma unroll
      for (int r = 0; r < 4; ++r) {
        float a = 0.f;
        #pragma unroll
        for (int t = 0; t < 13; ++t) a += wc.c[t] * win[(4 * it + r + t) % 24];
        vv[r] = a;
      }
    } else {
      #pragma unroll
      for (int r = 0; r < 4; ++r) {
        int yr = y + r;
        float a = 0.f;
        if (yr < 6) {
          #pragma unroll
          for (int t = 0; t < 13; ++t) a += wl[(yr << 4) + t] * win[(4 * it + r + t) % 24];
        } else if (yr > 249) {
          #pragma unroll
          for (int t = 0; t < 13; ++t) a += wl[((255 - yr) << 4) + (12 - t)] * win[(4 * it + r + t) % 24];
        } else {
          #pragma unroll
          for (int t = 0; t < 13; ++t) a += wc.c[t] * win[(4 * it + r + t) % 24];
        }
        vv[r] = a;
      }
    }
    const int buf = it & 1;
    #pragma unroll
    for (int r = 0; r < 4; ++r) {
      rb[buf][r][8 + tid] = vv[r];
      xrb[buf][r][tid] = win[(4 * it + 6 + r) % 24];
    }
    if (vsave) {
      #pragma unroll
      for (int r = 0; r < 4; ++r) vs[4 * it + r][vsidx] = vv[r];
    }
    __syncthreads();

    // horizontal conv: aligned b128 reads; cols 4q+j use f[2+j .. 14+j]
    const float* hp = &rb[buf][g][4 * q];
    float f[20];
    *(float4*)&f[0]  = *(const float4*)(hp + 0);
    *(float4*)&f[4]  = *(const float4*)(hp + 4);
    *(float4*)&f[8]  = *(const float4*)(hp + 8);
    *(float4*)&f[12] = *(const float4*)(hp + 12);
    *(float4*)&f[16] = *(const float4*)(hp + 16);
    float4 xq = *(const float4*)&xrb[buf][g][4 * q];
    float h0 = 0.f, h1 = 0.f, h2 = 0.f, h3 = 0.f;
    #pragma unroll
    for (int t = 0; t < 13; ++t) {
      float w = wc.c[t];
      h0 += w * f[2 + t]; h1 += w * f[3 + t]; h2 += w * f[4 + t]; h3 += w * f[5 + t];
    }
    unsigned short s0 = f2bf(xq.x - h0), s1 = f2bf(xq.y - h1);
    unsigned short s2 = f2bf(xq.z - h2), s3 = f2bf(xq.w - h3);
    *(ushort4*)(cgb + (size_t)(y + g) * 256 + 4 * q) = make_ushort4(s0, s1, s2, s3);
  }

  __syncthreads();
  // post-pass: exact h-conv for 12 edge cols x 64 rows from saved v-results
  #pragma unroll
  for (int k = 0; k < 3; ++k) {
    int e = k * 256 + tid;           // 768 elements
    int row = e / 12;
    int ce = e - row * 12;
    int col = (ce < 6) ? ce : (244 + ce);   // {0..5, 250..255}
    float h = 0.f;
    if (ce < 6) {
      #pragma unroll
      for (int t = 0; t < 13; ++t) {
        int vc = col - 6 + t;
        if (vc >= 0) h += wl[(col << 4) + t] * vs[row][vc];
      }
    } else {
      #pragma unroll
      for (int t = 0; t < 13; ++t) {
        int vc = col - 6 + t;
        if (vc < 256) h += wl[((255 - col) << 4) + (12 - t)] * vs[row][vc - 232];
      }
    }
    int yrow = y0 + row;
    float xval = xg[yrow * 256 + col];
    cgb[yrow * 256 + col] = f2bf(xval - h);
  }
}

// MFMA att: per batch b, att = P * C^T, P = exp(C), C = ctx[b] (64 x 65536 bf16).
// Each ctx element appears exactly once as an A-fragment element across the grid,
// so S[b,d] (softmax denominator) is accumulated here from the f32 exp values.
__global__ __launch_bounds__(256) void att_k(const unsigned short* __restrict__ ctxb,
                                             float* __restrict__ S,
                                             float* __restrict__ attacc) {
  const int t = threadIdx.x;
  const int wv = t >> 6, lane = t & 63;
  const int rw = lane & 15;        // A-row / B-col within 16
  const int kq = lane >> 4;        // k-subgroup (8 elems each)
  const int ci = blockIdx.x;       // 64 chunks of 1024
  const int b = blockIdx.y;        // 16 batches
  const unsigned short* cb = ctxb + ((size_t)b << 22);
  const int n0 = (ci << 10) + (kq << 3);

  const unsigned short* pA = cb + (((size_t)(16 * wv + rw)) << 16) + n0;
  const unsigned short* pB = cb + (((size_t)rw) << 16) + n0;

  f32x4 acc0 = {0.f, 0.f, 0.f, 0.f}, acc1 = acc0, acc2 = acc0, acc3 = acc0;
  float ssum = 0.f;

  #pragma unroll 8
  for (int ks = 0; ks < 1024; ks += 32) {
    bf16x8 av = *(const bf16x8*)(pA + ks);
    bf16x8 ev;
    const unsigned* au = (const unsigned*)&av;
    unsigned* eu = (unsigned*)&ev;
    #pragma unroll
    for (int j = 0; j < 4; ++j) {
      unsigned w = au[j];
      float elo = __expf(__uint_as_float(w << 16));
      float ehi = __expf(__uint_as_float(w & 0xffff0000u));
      ssum += elo + ehi;
      eu[j] = ((unsigned)f2bf(ehi) << 16) | (unsigned)f2bf(elo);
    }
    bf16x8 b0 = *(const bf16x8*)(pB + ks);
    bf16x8 b1 = *(const bf16x8*)(pB + (size_t)(16 << 16) + ks);
    bf16x8 b2 = *(const bf16x8*)(pB + (size_t)(32 << 16) + ks);
    bf16x8 b3 = *(const bf16x8*)(pB + (size_t)(48 << 16) + ks);
    acc0 = __builtin_amdgcn_mfma_f32_16x16x32_bf16(ev, b0, acc0, 0, 0, 0);
    acc1 = __builtin_amdgcn_mfma_f32_16x16x32_bf16(ev, b1, acc1, 0, 0, 0);
    acc2 = __builtin_amdgcn_mfma_f32_16x16x32_bf16(ev, b2, acc2, 0, 0, 0);
    acc3 = __builtin_amdgcn_mfma_f32_16x16x32_bf16(ev, b3, acc3, 0, 0, 0);
  }

  // S row-sum: lanes {rw, rw+16, rw+32, rw+48} hold partials for row 16wv+rw
  ssum += __shfl_xor(ssum, 16);
  ssum += __shfl_xor(ssum, 32);
  if (lane < 16) atomicAdd(&S[(b << 6) + (wv << 4) + rw], ssum);

  // C/D layout: col = lane&15, row = (lane>>4)*4 + reg
  const int dl = kq << 2;
  float* ap = attacc + (((size_t)((b << 6) + (wv << 4) + dl)) << 6) + rw;
  #pragma unroll
  for (int reg = 0; reg < 4; ++reg) {
    atomicAdd(ap + ((size_t)reg << 6) + 0,  acc0[reg]);
    atomicAdd(ap + ((size_t)reg << 6) + 16, acc1[reg]);
    atomicAdd(ap + ((size_t)reg << 6) + 32, acc2[reg]);
    atomicAdd(ap + ((size_t)reg << 6) + 48, acc3[reg]);
  }
}

__global__ __launch_bounds__(256) void fin_k(float* __restrict__ out, const float* __restrict__ S) {
  int i = blockIdx.x * 256 + threadIdx.x;  // 65536 = 16*64*64
  out[i] = out[i] / S[i >> 6];
}

extern "C" void kernel_launch(void* const* d_in, const int* in_sizes, int n_in,
                              void* d_out, int out_size, void* d_ws, size_t ws_size,
                              hipStream_t stream) {
  const float* x = (const float*)d_in[0];
  float* out = (float*)d_out;
  unsigned short* ctxb = (unsigned short*)d_ws;                        // 134 MiB bf16
  float* S    = (float*)((char*)d_ws + (size_t)67108864 * 2);          // 4 KB
  float* wtab = (float*)((char*)d_ws + (size_t)67108864 * 2 + 4096);   // 16 KB
  if (ws_size < (size_t)67108864 * 2 + 4096 + 16384) return;

  // per-level 1-D gaussians in double (matches cv2.getGaussianKernel)
  double gg[3][7];
  double sv = pow(2.0, 1.0 / 3.0);
  for (int lv = 0; lv < 3; ++lv) {
    int k = 2 * lv + 3;
    double sig = 1.6 * pow(sv, lv), sum = 0.0;
    for (int i = 0; i < k; ++i) {
      double a = i - (k - 1) / 2.0;
      gg[lv][i] = exp(-a * a / (2.0 * sig * sig));
      sum += gg[lv][i];
    }
    for (int i = 0; i < k; ++i) gg[lv][i] /= sum;
  }

  G157 gw;
  for (int i = 0; i < 3; ++i) gw.g3[i] = (float)gg[0][i];
  for (int i = 0; i < 5; ++i) gw.g5[i] = (float)gg[1][i];
  for (int i = 0; i < 7; ++i) gw.g7[i] = (float)gg[2][i];

  WC wc;
  {
    double t35[7] = {0};
    for (int i = 0; i < 3; ++i)
      for (int j = 0; j < 5; ++j) t35[i + j] += gg[0][i] * gg[1][j];
    double t357[13] = {0};
    for (int i = 0; i < 7; ++i)
      for (int j = 0; j < 7; ++j) t357[i + j] += t35[i] * gg[2][j];
    for (int t = 0; t < 13; ++t) wc.c[t] = (float)t357[t];
  }

  zero_k<<<dim3(256), dim3(256), 0, stream>>>(out, S, wtab, gw);
  ctx_k<<<dim3(4096), dim3(256), 0, stream>>>(x, ctxb, wtab, wc);
  att_k<<<dim3(64, 16), dim3(256), 0, stream>>>(ctxb, S, out);
  fin_k<<<dim3(256), dim3(256), 0, stream>>>(out, S);
}